// Round 9
// baseline (47.493 us; speedup 1.0000x reference)
//
#include <hip/hip_runtime.h>
#include <math.h>

// DeepFeatureLoss: B=2, N=4096, D=32, fp32 in/out.
// out[0..1] = ce_loss[b], out[2..3] = reg_loss[b].
//
// ce_i = log(s_f) - t/s_p  (softmax max pinned at 0; dists <= 0):
//   s_p = sum_j exp(pd_ij), t = sum_j exp(pd_ij)*fd_ij, s_f = sum_j exp(fd_ij)
// All exponents in log2 units (bare v_exp_f32); t *= LN2 at finalize.
//
// R9: instruction-count attack (R2..R8 invariant ~33us => issue/exec-bound,
// likely at low DPM clock; ILP/TLP/VMEM all falsified).
//  * point dist2 via 2nd f16 MFMA with hi/lo split (12 channels:
//    hi*hi + hi*lo + lo*hi + lo*lo per coord). Error ~0.1 log2-units,
//    same order as the reference's own fp32 GEMM-expansion noise; cancels
//    in t/sp ratio.
//  * C-operand folding: C = -n_row - n_col so MFMA outputs fd / parg
//    directly. Epilogue ~5 f4 ops + 2 exp2 per 4 outputs.
//  * sparsity skip: sigma=0.005 => only ~5% of tiles have any parg > -80;
//    wave-uniform __any + scalar branch skips ep/sp/tA (bit-identical:
//    2^-80 contributions vanish in fp32 sums).
//
// ws (floats): fragFA@0(131072) fragFB@131072 fragPA@262144(131072)
// fragPB@393216 qn1@524288(16384) pw2s@540672(16384) regp@557056(8192).

#define NPTS 4096
#define ROWS_TOT 8192
#define DF 32
#define NTILE 512                 // 16-row i-tiles across both batches

#define L2E  1.4426950408889634f
#define LN2  0.6931471805599453f
#define FSC  1.6986436f           // sqrt(2*log2e)
#define PSC2 339.72872f           // 200*sqrt(2*log2e)
#define SKIP_THR (-80.0f)

typedef _Float16 half8 __attribute__((ext_vector_type(8)));
typedef float f4 __attribute__((ext_vector_type(4)));

// ---- kA: prep fragments + norm planes + reg plane ----
__global__ void kA_prep(const float* __restrict__ pts,
                        const float* __restrict__ f1g,
                        const float* __restrict__ f2g,
                        _Float16* __restrict__ fragFA, _Float16* __restrict__ fragFB,
                        _Float16* __restrict__ fragPA, _Float16* __restrict__ fragPB,
                        float2* __restrict__ qn1, float2* __restrict__ pw2s,
                        float* __restrict__ regp, float* __restrict__ out) {
    const int r = blockIdx.x * 64 + threadIdx.x;     // 0..8191
    if (r < 4) out[r] = 0.0f;
    const int jt = r >> 4;                           // global tile id 0..511
    const int c  = r & 15;                           // row/col within tile

    float n1, n2, reg1, reg2;
    {   // f2 -> B-layout feature fragments
        const float4* fv4 = (const float4*)(f2g + (size_t)r * DF);
        float vals[32]; float s = 0.0f;
#pragma unroll
        for (int q = 0; q < 8; ++q) {
            float4 v = fv4[q];
            vals[4*q]=v.x; vals[4*q+1]=v.y; vals[4*q+2]=v.z; vals[4*q+3]=v.w;
            s += v.x*v.x + v.y*v.y + v.z*v.z + v.w*v.w;
        }
        n2 = s;
        reg2 = s - vals[0]*vals[0] - vals[1]*vals[1] - vals[2]*vals[2];
        half8* fv = (half8*)fragFB;
#pragma unroll
        for (int kb = 0; kb < 4; ++kb) {
            half8 h;
#pragma unroll
            for (int i = 0; i < 8; ++i) h[i] = (_Float16)(vals[kb*8+i] * FSC);
            fv[(size_t)jt*64 + kb*16 + c] = h;
        }
    }
    {   // f1 -> A-layout feature fragments
        const float4* fv4 = (const float4*)(f1g + (size_t)r * DF);
        float vals[32]; float s = 0.0f;
#pragma unroll
        for (int q = 0; q < 8; ++q) {
            float4 v = fv4[q];
            vals[4*q]=v.x; vals[4*q+1]=v.y; vals[4*q+2]=v.z; vals[4*q+3]=v.w;
            s += v.x*v.x + v.y*v.y + v.z*v.z + v.w*v.w;
        }
        n1 = s;
        reg1 = s - vals[0]*vals[0] - vals[1]*vals[1] - vals[2]*vals[2];
        half8* fv = (half8*)fragFA;
#pragma unroll
        for (int kb = 0; kb < 4; ++kb) {
            half8 h;
#pragma unroll
            for (int i = 0; i < 8; ++i) h[i] = (_Float16)(vals[kb*8+i] * FSC);
            fv[(size_t)jt*64 + kb*16 + c] = h;
        }
    }
    {   // points: hi/lo split channels; np' = 0.5*|p*PSC2|^2 (log2 units)
        const float* pp = pts + (size_t)r * 3;
        const float v0 = pp[0]*PSC2, v1 = pp[1]*PSC2, v2 = pp[2]*PSC2;
        const float h0 = (float)(_Float16)v0, h1 = (float)(_Float16)v1,
                    h2 = (float)(_Float16)v2;
        const float l0 = v0 - h0, l1 = v1 - h1, l2 = v2 - h2;
        const float np = 0.5f * (v0*v0 + v1*v1 + v2*v2);

        const float pa[16] = {h0,h1,h2,l0,l1,l2,h0,h1,  h2,l0,l1,l2,0,0,0,0};
        const float pb[16] = {h0,h1,h2,h0,h1,h2,l0,l1,  l2,l0,l1,l2,0,0,0,0};
        half8* fa = (half8*)fragPA;
        half8* fb = (half8*)fragPB;
#pragma unroll
        for (int kb = 0; kb < 2; ++kb) {
            half8 ha, hb;
#pragma unroll
            for (int i = 0; i < 8; ++i) {
                ha[i] = (_Float16)pa[kb*8+i];
                hb[i] = (_Float16)pb[kb*8+i];
            }
            fa[(size_t)jt*64 + kb*16 + c] = ha;
            fb[(size_t)jt*64 + kb*16 + c] = hb;
        }
        const half8 z = {0,0,0,0,0,0,0,0};
        fa[(size_t)jt*64 + 32 + c] = z;  fa[(size_t)jt*64 + 48 + c] = z;
        fb[(size_t)jt*64 + 32 + c] = z;  fb[(size_t)jt*64 + 48 + c] = z;

        qn1[r]  = make_float2(-(n1 * L2E), -np);     // row-side (negated)
        pw2s[r] = make_float2(  n2 * L2E,   np);     // col-side (positive)
    }
    regp[r] = reg1 + reg2;
}

// ---- kB: 1 block per i-tile; 8 waves x 32 j-tiles; 2 MFMAs + skip ----
__launch_bounds__(512, 4)
__global__ void kB_main(const _Float16* __restrict__ fragFA,
                        const _Float16* __restrict__ fragFB,
                        const _Float16* __restrict__ fragPA,
                        const _Float16* __restrict__ fragPB,
                        const float2* __restrict__ qn1,
                        const float2* __restrict__ pw2s,
                        const float* __restrict__ regp,
                        const float* __restrict__ wg,
                        float* __restrict__ out) {
    __shared__ float sS[8][16], sT[8][16], sF[8][16];

    const int tid = threadIdx.x;
    const int l = tid & 63, wv = tid >> 6;           // wave 0..7
    const int i_tile = blockIdx.x;                   // 0..511
    const int b = i_tile >> 8;
    const int i0g = i_tile * 16;
    const int lr = l & 15, lk = l >> 4;

    const half8 afF = ((const half8*)fragFA)[(size_t)i_tile * 64 + l];
    const half8 afP = ((const half8*)fragPA)[(size_t)i_tile * 64 + l];

    const int rbase = i0g + lk * 4;                  // this lane's 4 rows
    const float2 qa = qn1[rbase + 0];
    const float2 qb = qn1[rbase + 1];
    const float2 qc = qn1[rbase + 2];
    const float2 qd = qn1[rbase + 3];
    const f4 qwfn = {qa.x, qb.x, qc.x, qd.x};        // -nf1' per row
    const f4 qwpn = {qa.y, qb.y, qc.y, qd.y};        // -np1' per row

    // wave's j range: tiles jt0+t, cols j0+t*16, t=0..31
    const int jt0 = b * 256 + wv * 32;
    const int j0  = b * NPTS + wv * 512 + lr;
    const half8*  fbF = (const half8*)fragFB + ((size_t)jt0 * 64 + l);
    const half8*  fbP = (const half8*)fragPB + ((size_t)jt0 * 64 + l);
    const float2* pb  = pw2s + j0;

    f4 sp = {0,0,0,0}, tA = {0,0,0,0}, sf = {0,0,0,0};

    half8  bFc = fbF[0];
    half8  bPc = fbP[0];
    float2 pwc = pb[0];
#pragma unroll
    for (int t = 0; t < 32; ++t) {
        half8 bFn = bFc; half8 bPn = bPc; float2 pwn = pwc;
        if (t < 31) {                                // 1-deep prefetch
            bFn = fbF[(t + 1) * 64];
            bPn = fbP[(t + 1) * 64];
            pwn = pb[(t + 1) * 16];
        }
        const f4 C1 = qwfn - pwc.x;                  // -(nf1'+nf2')
        const f4 C2 = qwpn - pwc.y;                  // -(np1'+np2')
        const f4 fd   = __builtin_amdgcn_mfma_f32_16x16x32_f16(afF, bFc, C1, 0, 0, 0);
        const f4 parg = __builtin_amdgcn_mfma_f32_16x16x32_f16(afP, bPc, C2, 0, 0, 0);

        f4 ef;
#pragma unroll
        for (int e = 0; e < 4; ++e) ef[e] = __builtin_amdgcn_exp2f(fd[e]);
        sf += ef;

        const float m = fmaxf(fmaxf(parg[0], parg[1]), fmaxf(parg[2], parg[3]));
        if (__any(m > SKIP_THR)) {                   // ~5% of tiles + diagonal
            f4 ep;
#pragma unroll
            for (int e = 0; e < 4; ++e) ep[e] = __builtin_amdgcn_exp2f(parg[e]);
            sp += ep;
            tA += ep * fd;
        }
        bFc = bFn; bPc = bPn; pwc = pwn;
    }

    // reduce over the 16 columns (lane bits 0..3)
#pragma unroll
    for (int m = 1; m < 16; m <<= 1) {
#pragma unroll
        for (int e = 0; e < 4; ++e) {
            sp[e] += __shfl_xor(sp[e], m);
            tA[e] += __shfl_xor(tA[e], m);
            sf[e] += __shfl_xor(sf[e], m);
        }
    }
    if (lr == 0) {
#pragma unroll
        for (int e = 0; e < 4; ++e) {
            sS[wv][lk * 4 + e] = sp[e];
            sT[wv][lk * 4 + e] = tA[e];
            sF[wv][lk * 4 + e] = sf[e];
        }
    }
    __syncthreads();

    if (tid < 16) {
        float sp_ = 0.f, tp_ = 0.f, sf_ = 0.f;
#pragma unroll
        for (int w = 0; w < 8; ++w) {
            sp_ += sS[w][tid];
            tp_ += sT[w][tid];
            sf_ += sF[w][tid];
        }
        const int r = i0g + tid;
        const float ce = __logf(sf_) - (tp_ * LN2) / sp_;
        float contrib = wg[r] * ce;
        float rr = regp[r];
#pragma unroll
        for (int m = 1; m < 16; m <<= 1) {           // lanes 0..15 only
            contrib += __shfl_xor(contrib, m);
            rr      += __shfl_xor(rr, m);
        }
        if (tid == 0) {
            atomicAdd(&out[b],     contrib);
            atomicAdd(&out[2 + b], rr * (1.0f / (29.0f * (float)NPTS)));
        }
    }
}

extern "C" void kernel_launch(void* const* d_in, const int* in_sizes, int n_in,
                              void* d_out, int out_size, void* d_ws, size_t ws_size,
                              hipStream_t stream) {
    const float* pts = (const float*)d_in[0];
    const float* f1  = (const float*)d_in[1];
    const float* f2  = (const float*)d_in[2];
    const float* wg  = (const float*)d_in[3];
    float* out = (float*)d_out;

    float* ws = (float*)d_ws;
    _Float16* fragFA = (_Float16*)(ws);              // 262144 halves
    _Float16* fragFB = (_Float16*)(ws + 131072);
    _Float16* fragPA = (_Float16*)(ws + 262144);
    _Float16* fragPB = (_Float16*)(ws + 393216);
    float2*   qn1    = (float2*)(ws + 524288);       // 8192 float2
    float2*   pw2s   = (float2*)(ws + 540672);       // 8192 float2
    float*    regp   = ws + 557056;                  // 8192

    kA_prep<<<ROWS_TOT / 64, 64, 0, stream>>>(pts, f1, f2,
                                              fragFA, fragFB, fragPA, fragPB,
                                              qn1, pw2s, regp, out);
    kB_main<<<NTILE, 512, 0, stream>>>(fragFA, fragFB, fragPA, fragPB,
                                       qn1, pw2s, regp, wg, out);
}

// Round 10
// 38.529 us; speedup vs baseline: 1.2327x; 1.2327x over previous
//
#include <hip/hip_runtime.h>
#include <math.h>

// DeepFeatureLoss: B=2, N=4096, D=32, fp32 in/out.
// out[0..1] = ce_loss[b], out[2..3] = reg_loss[b].
//
// ce_i = log(s_f) - t/s_p  (softmax max pinned at 0; dists <= 0):
//   s_p = sum_j exp(pd_ij), t = sum_j exp(pd_ij)*fd_ij, s_f = sum_j exp(fd_ij)
// exp2 folding: points *PSC, features *FSC, norms *L2E; t *= LN2 at end.
//
// R10 = R6 (best, 33.0us) + ONE change: v_exp_f32 (trans pipe, 1/4..1/8
// rate sharing the VALU issue port -> dominant cost 128-256cyc/iter)
// replaced by a full-rate VALU poly: 2^x = ldexp(poly3(x-rint x), rint x)
// = 7 VALU ops. Plus free C-operand fold (n1 pre-negated -> MFMA emits fd
// directly) and fma-modifier negation for the point dist.
//
// ws (floats): pp1[0,32768) pp2[32768,65536) fragB[65536,196608)
// fragA[196608,327680) regp[327680,335872).

#define NPTS 4096
#define ROWS_TOT 8192
#define DF 32
#define NTILE 512                // 16-row i-tiles across both batches

#define L2E  1.4426950408889634f
#define LN2  0.6931471805599453f
#define FSC  1.6986436f          // sqrt(2*log2e)
#define PSC  240.2244f           // 200*sqrt(log2e)

typedef _Float16 half8 __attribute__((ext_vector_type(8)));
typedef float f4 __attribute__((ext_vector_type(4)));

// 2^x via full-rate VALU: rndne+sub+3fma+cvt+ldexp (7 ops), rel err ~1e-5.
// Valid for any x<=0 incl. huge negatives (ldexp underflows to +0).
static __device__ __forceinline__ float exp2p(float x) {
    const float kf = __builtin_rintf(x);
    const float f  = x - kf;
    float p = fmaf(f, 0.0555041086f, 0.2402265069f);
    p = fmaf(f, p, 0.6931471806f);
    p = fmaf(f, p, 1.0f);
    return __builtin_ldexpf(p, (int)kf);
}

// ---- kA: prep ----
__global__ void kA_prep(const float* __restrict__ pts,
                        const float* __restrict__ f1g,
                        const float* __restrict__ f2g,
                        float* __restrict__ pp1, float* __restrict__ pp2,
                        _Float16* __restrict__ fragA, _Float16* __restrict__ fragB,
                        float* __restrict__ regp, float* __restrict__ out) {
    const int r = blockIdx.x * 64 + threadIdx.x;     // 0..8191
    if (r < 4) out[r] = 0.0f;
    const int jt = r >> 4;                           // global tile id 0..511
    const int c  = r & 15;                           // row/col within tile

    float n1, n2, reg1, reg2;
    {
        const float4* f2v = (const float4*)(f2g + (size_t)r * DF);
        float vals[32];
        float s = 0.0f;
#pragma unroll
        for (int q = 0; q < 8; ++q) {
            float4 v = f2v[q];
            vals[4*q]=v.x; vals[4*q+1]=v.y; vals[4*q+2]=v.z; vals[4*q+3]=v.w;
            s += v.x*v.x + v.y*v.y + v.z*v.z + v.w*v.w;
        }
        n2 = s;
        reg2 = s - vals[0]*vals[0] - vals[1]*vals[1] - vals[2]*vals[2];
        half8* fv = (half8*)fragB;
#pragma unroll
        for (int kb = 0; kb < 4; ++kb) {             // lane-ordered slot
            half8 h;
#pragma unroll
            for (int i = 0; i < 8; ++i) h[i] = (_Float16)(vals[kb*8+i] * FSC);
            fv[(size_t)jt*64 + kb*16 + c] = h;
        }
    }
    {
        const float4* f1v = (const float4*)(f1g + (size_t)r * DF);
        float vals[32];
        float s = 0.0f;
#pragma unroll
        for (int q = 0; q < 8; ++q) {
            float4 v = f1v[q];
            vals[4*q]=v.x; vals[4*q+1]=v.y; vals[4*q+2]=v.z; vals[4*q+3]=v.w;
            s += v.x*v.x + v.y*v.y + v.z*v.z + v.w*v.w;
        }
        n1 = s;
        reg1 = s - vals[0]*vals[0] - vals[1]*vals[1] - vals[2]*vals[2];
        half8* fv = (half8*)fragA;
#pragma unroll
        for (int kb = 0; kb < 4; ++kb) {
            half8 h;
#pragma unroll
            for (int i = 0; i < 8; ++i) h[i] = (_Float16)(vals[kb*8+i] * FSC);
            fv[(size_t)jt*64 + kb*16 + c] = h;
        }
    }
    const float* pp = pts + (size_t)r * 3;
    const float px = pp[0]*PSC, py = pp[1]*PSC, pz = pp[2]*PSC;
    ((float4*)pp1)[r] = make_float4(px, py, pz, -(n1 * L2E));   // NEGATED
    ((float4*)pp2)[r] = make_float4(px, py, pz, n2 * L2E);
    regp[r] = reg1 + reg2;
}

// ---- kB: one block per i-tile; 8 waves x 32 j-tiles; prefetched loop ----
__launch_bounds__(512)
__global__ void kB_main(const float* __restrict__ pp1,
                        const float* __restrict__ pp2,
                        const _Float16* __restrict__ fragA,
                        const _Float16* __restrict__ fragB,
                        const float* __restrict__ regp,
                        const float* __restrict__ wg,
                        float* __restrict__ out) {
    __shared__ float sS[8][16], sT[8][16], sF[8][16];

    const int tid = threadIdx.x;
    const int l = tid & 63, wv = tid >> 6;           // wave 0..7
    const int i_tile = blockIdx.x;                   // 0..511
    const int b = i_tile >> 8;
    const int i0g = i_tile * 16;                     // global row base
    const int lr = l & 15, lk = l >> 4;

    const half8 afrag = ((const half8*)fragA)[(size_t)i_tile * 64 + l];

    const int rbase = i0g + lk * 4;                  // this lane's 4 rows
    const float4 q0 = ((const float4*)pp1)[rbase + 0];
    const float4 q1 = ((const float4*)pp1)[rbase + 1];
    const float4 q2 = ((const float4*)pp1)[rbase + 2];
    const float4 q3 = ((const float4*)pp1)[rbase + 3];
    const f4 qx = {q0.x, q1.x, q2.x, q3.x};
    const f4 qy = {q0.y, q1.y, q2.y, q3.y};
    const f4 qz = {q0.z, q1.z, q2.z, q3.z};
    const f4 qw = {q0.w, q1.w, q2.w, q3.w};          // = -n1' per row

    // wave's j range: frag tile (b*256 + wv*32 + t), rows
    // b*4096 + wv*512 + t*16 + lr  -- both strides constant in t.
    const half8*  fbase = (const half8*)fragB + ((size_t)(b * 256 + wv * 32) * 64 + l);
    const float4* pbase = (const float4*)pp2 + (b * NPTS + wv * 512 + lr);

    f4 sp = {0,0,0,0}, tA = {0,0,0,0}, sf = {0,0,0,0};

    half8  bfA = fbase[0];
    float4 pwA = pbase[0];
#pragma unroll
    for (int t = 0; t < 32; ++t) {
        half8  bfN = bfA;
        float4 pwN = pwA;
        if (t < 31) {                                // 1-deep prefetch
            bfN = fbase[(t + 1) * 64];
            pwN = pbase[(t + 1) * 16];
        }
        const f4 C1 = qw - pwA.w;                    // -(n1'+n2')
        const f4 fd = __builtin_amdgcn_mfma_f32_16x16x32_f16(afrag, bfA, C1, 0, 0, 0);
        const f4 dx = qx - pwA.x;
        const f4 dy = qy - pwA.y;
        const f4 dz = qz - pwA.z;
        const f4 sneg = -dx*dx - dy*dy - dz*dz;      // -log2e*|dp|^2 (neg mods free)
        f4 ep, ef;
#pragma unroll
        for (int e = 0; e < 4; ++e) {
            ep[e] = exp2p(sneg[e]);
            ef[e] = exp2p(fd[e]);
        }
        sp += ep;
        tA += ep * fd;
        sf += ef;
        bfA = bfN;
        pwA = pwN;
    }

    // reduce over the 16 columns (lane bits 0..3)
#pragma unroll
    for (int m = 1; m < 16; m <<= 1) {
#pragma unroll
        for (int e = 0; e < 4; ++e) {
            sp[e] += __shfl_xor(sp[e], m);
            tA[e] += __shfl_xor(tA[e], m);
            sf[e] += __shfl_xor(sf[e], m);
        }
    }
    if (lr == 0) {
#pragma unroll
        for (int e = 0; e < 4; ++e) {
            sS[wv][lk * 4 + e] = sp[e];
            sT[wv][lk * 4 + e] = tA[e];
            sF[wv][lk * 4 + e] = sf[e];
        }
    }
    __syncthreads();

    if (tid < 16) {
        float sp_ = 0.f, tp_ = 0.f, sf_ = 0.f;
#pragma unroll
        for (int w = 0; w < 8; ++w) {
            sp_ += sS[w][tid];
            tp_ += sT[w][tid];
            sf_ += sF[w][tid];
        }
        const int r = i0g + tid;
        const float ce = __logf(sf_) - (tp_ * LN2) / sp_;
        float contrib = wg[r] * ce;
        float rr = regp[r];
#pragma unroll
        for (int m = 1; m < 16; m <<= 1) {           // lanes 0..15 only
            contrib += __shfl_xor(contrib, m);
            rr      += __shfl_xor(rr, m);
        }
        if (tid == 0) {
            atomicAdd(&out[b],     contrib);
            atomicAdd(&out[2 + b], rr * (1.0f / (29.0f * (float)NPTS)));
        }
    }
}

extern "C" void kernel_launch(void* const* d_in, const int* in_sizes, int n_in,
                              void* d_out, int out_size, void* d_ws, size_t ws_size,
                              hipStream_t stream) {
    const float* pts = (const float*)d_in[0];
    const float* f1  = (const float*)d_in[1];
    const float* f2  = (const float*)d_in[2];
    const float* wg  = (const float*)d_in[3];
    float* out = (float*)d_out;

    float* ws = (float*)d_ws;
    float*     pp1   = ws;                           // 32768
    float*     pp2   = ws + 32768;                   // 32768
    _Float16*  fragB = (_Float16*)(ws + 65536);      // 262144 halves
    _Float16*  fragA = (_Float16*)(ws + 196608);     // 262144 halves
    float*     regp  = ws + 327680;                  // 8192

    kA_prep<<<ROWS_TOT / 64, 64, 0, stream>>>(pts, f1, f2, pp1, pp2,
                                              fragA, fragB, regp, out);
    kB_main<<<NTILE, 512, 0, stream>>>(pp1, pp2, fragA, fragB, regp, wg, out);
}